// Round 3
// baseline (1058.480 us; speedup 1.0000x reference)
//
#include <hip/hip_runtime.h>
#include <hip/hip_cooperative_groups.h>

namespace cg = cooperative_groups;

#define DF 64       // feature dim
#define WSTRIDE 132 // LDS row stride for W (mult of 4 keeps 16B align; %32==4 spreads banks)
#define CSR_BLOCKS 768
#define CSR_THREADS 256

// ---------------------------------------------------------------------------
// One cooperative kernel does the whole CSR build:
//   zero counts -> count degrees -> hierarchical exclusive scan -> fill lists
// grid.sync() between phases replaces 6 separate dispatches.
// ---------------------------------------------------------------------------
__global__ __launch_bounds__(CSR_THREADS) void build_csr(
    const int* __restrict__ src, const int* __restrict__ dst,
    int* cnt, int* part, int* bsum, int* boff,
    int* offsets, int* cursor, int* eidx, int N, int E)
{
    cg::grid_group grid = cg::this_grid();
    __shared__ int wsum[4];

    const int t = threadIdx.x;
    const int gid = blockIdx.x * CSR_THREADS + t;
    const int gsz = gridDim.x * CSR_THREADS;
    const int lane = t & 63, w = t >> 6;

    // phase 1: zero counters (ws is poisoned 0xAA before every launch)
    for (int i = gid; i < N; i += gsz) cnt[i] = 0;
    grid.sync();

    // phase 2: per-destination degree count
    for (int e = gid; e < E; e += gsz) atomicAdd(&cnt[dst[e]], 1);
    grid.sync();

    // phase 3: block-local scan, 1024 counts per block (first nb blocks)
    const int nb = (N + 1023) / 1024;  // 98 for N=100k; must be <= 256
    if (blockIdx.x < nb) {
        int base = blockIdx.x * 1024 + t * 4;
        int4 v = make_int4(0, 0, 0, 0);
        if (base + 3 < N) {
            v = *(const int4*)&cnt[base];
        } else {
            if (base     < N) v.x = cnt[base];
            if (base + 1 < N) v.y = cnt[base + 1];
            if (base + 2 < N) v.z = cnt[base + 2];
            if (base + 3 < N) v.w = cnt[base + 3];
        }
        int s = v.x + v.y + v.z + v.w;
        int sc = s;
        #pragma unroll
        for (int m = 1; m < 64; m <<= 1) {
            int u = __shfl_up(sc, m);
            if (lane >= m) sc += u;
        }
        if (lane == 63) wsum[w] = sc;
        __syncthreads();
        int woff = 0;
        for (int i = 0; i < w; ++i) woff += wsum[i];
        int excl = woff + sc - s;
        if (base     < N) part[base]     = excl;
        if (base + 1 < N) part[base + 1] = excl + v.x;
        if (base + 2 < N) part[base + 2] = excl + v.x + v.y;
        if (base + 3 < N) part[base + 3] = excl + v.x + v.y + v.z;
        if (t == 255) bsum[blockIdx.x] = woff + sc;  // block total
    }
    grid.sync();

    // phase 4: block 0 scans the block totals (nb <= 256)
    if (blockIdx.x == 0) {
        int v = (t < nb) ? bsum[t] : 0;
        int sc = v;
        #pragma unroll
        for (int m = 1; m < 64; m <<= 1) {
            int u = __shfl_up(sc, m);
            if (lane >= m) sc += u;
        }
        if (lane == 63) wsum[w] = sc;
        __syncthreads();
        int woff = 0;
        for (int i = 0; i < w; ++i) woff += wsum[i];
        if (t < nb) boff[t] = woff + sc - v;  // exclusive
    }
    grid.sync();

    // phase 5: globalize offsets, init cursors
    for (int i = gid; i < N; i += gsz) {
        int o = part[i] + boff[i >> 10];
        offsets[i] = o;
        cursor[i]  = o;
    }
    if (gid == 0) offsets[N] = E;
    grid.sync();

    // phase 6: scatter edge sources into per-destination segments
    for (int e = gid; e < E; e += gsz) {
        int p = atomicAdd(&cursor[dst[e]], 1);
        eidx[p] = src[e];
    }
}

// ---------------------------------------------------------------------------
// Fused gather + update. One wave per node, lane = feature index.
// 512-thread blocks so 8 waves share one LDS copy of W:
//   LDS = 33KB(W)+4KB(xbuf) -> 4 blocks/CU * 8 waves = 32 waves/CU ceiling.
// __launch_bounds__(512,8) caps VGPRs at 64 to allow 8 waves/SIMD.
// ---------------------------------------------------------------------------
__global__ __launch_bounds__(512, 8) void sage_fused(
    const float* __restrict__ h, const float* __restrict__ W,
    const float* __restrict__ b, const int* __restrict__ offsets,
    const int* __restrict__ eidx, float* __restrict__ out, int N)
{
    __shared__ float Wp[DF * WSTRIDE];   // ~33 KB
    __shared__ float bs[DF];
    __shared__ float xbuf[8][128];

    for (int i = threadIdx.x; i < DF * 128; i += 512) {
        int o = i >> 7, k = i & 127;
        Wp[o * WSTRIDE + k] = W[i];
    }
    if (threadIdx.x < DF) bs[threadIdx.x] = b[threadIdx.x];
    __syncthreads();

    const int wave = threadIdx.x >> 6;
    const int lane = threadIdx.x & 63;
    const int gw = blockIdx.x * 8 + wave;
    const int nw = gridDim.x * 8;
    float* xb = xbuf[wave];
    const float* wrow = &Wp[lane * WSTRIDE];
    const float bias = bs[lane];

    for (int n = gw; n < N; n += nw) {
        int beg = offsets[n];
        int end = offsets[n + 1];
        float hv = h[(size_t)n * DF + lane];

        // --- gather-sum neighbors: 4 independent accumulators for MLP ---
        float a0 = 0.f, a1 = 0.f, a2 = 0.f, a3 = 0.f;
        for (int base = beg; base < end; base += 64) {
            int m = end - base;
            if (m > 64) m = 64;
            int idx = 0;
            if (lane < m) idx = eidx[base + lane];
            int j = 0;
            for (; j + 3 < m; j += 4) {
                int s0 = __shfl(idx, j);
                int s1 = __shfl(idx, j + 1);
                int s2 = __shfl(idx, j + 2);
                int s3 = __shfl(idx, j + 3);
                a0 += h[(size_t)s0 * DF + lane];
                a1 += h[(size_t)s1 * DF + lane];
                a2 += h[(size_t)s2 * DF + lane];
                a3 += h[(size_t)s3 * DF + lane];
            }
            for (; j < m; ++j) {
                int s0 = __shfl(idx, j);
                a0 += h[(size_t)s0 * DF + lane];
            }
        }
        float dg = (float)(end - beg);
        float cv = ((a0 + a1) + (a2 + a3)) / fmaxf(dg, 1.0f);

        // --- update: y = [h,c]·W^T + b ---
        xb[lane] = hv;
        xb[DF + lane] = cv;   // wave-synchronous LDS, no block barrier needed

        float y = bias;
        #pragma unroll
        for (int k = 0; k < 128; k += 4) {
            float4 xk = *(const float4*)&xb[k];    // same-address broadcast
            float4 wk = *(const float4*)&wrow[k];
            y += xk.x * wk.x;
            y += xk.y * wk.y;
            y += xk.z * wk.z;
            y += xk.w * wk.w;
        }

        // L2 norm across 64 lanes
        float ss = y * y;
        #pragma unroll
        for (int m = 1; m < 64; m <<= 1) ss += __shfl_xor(ss, m);

        float norm = sqrtf(ss);
        float nb2 = y / fmaxf(norm, 1e-12f);
        float nh = fmaxf(nb2, 0.0f);
        float hupd = (dg > 0.0f) ? nh : hv;
        out[(size_t)n * DF + lane] = hv + hupd;
    }
}

extern "C" void kernel_launch(void* const* d_in, const int* in_sizes, int n_in,
                              void* d_out, int out_size, void* d_ws, size_t ws_size,
                              hipStream_t stream) {
    const float* h   = (const float*)d_in[0];
    const float* W   = (const float*)d_in[1];
    const float* b   = (const float*)d_in[2];
    const int*   src = (const int*)d_in[3];
    const int*   dst = (const int*)d_in[4];
    float* out = (float*)d_out;

    int N = in_sizes[0] / DF;
    int E = in_sizes[3];

    // workspace carve (ints, 16B-aligned sections)
    int* cnt     = (int*)d_ws;                 // N
    int* part    = cnt     + ((N + 15) & ~15); // N
    int* bsum    = part    + ((N + 15) & ~15); // 256
    int* boff    = bsum    + 256;              // 256
    int* offsets = boff    + 256;              // N+1
    int* cursor  = offsets + ((N + 16) & ~15); // N
    int* eidx    = cursor  + ((N + 15) & ~15); // E

    void* args[] = { (void*)&src, (void*)&dst, (void*)&cnt, (void*)&part,
                     (void*)&bsum, (void*)&boff, (void*)&offsets,
                     (void*)&cursor, (void*)&eidx, (void*)&N, (void*)&E };
    hipLaunchCooperativeKernel((const void*)build_csr, dim3(CSR_BLOCKS),
                               dim3(CSR_THREADS), args, 0, stream);

    sage_fused<<<1024, 512, 0, stream>>>(h, W, b, offsets, eidx, out, N);
}

// Round 4
// 431.111 us; speedup vs baseline: 2.4552x; 2.4552x over previous
//
#include <hip/hip_runtime.h>

#define DF 64       // feature dim
#define WSTRIDE 132 // LDS row stride for W (mult of 4 keeps 16B align; %32==4 spreads banks)

// ---------------------------------------------------------------------------
// CSR build pass 1: per-destination degree count. int4-batched: 4 edges per
// thread -> 4 independent atomics in flight, 1/4 the waves.
// ---------------------------------------------------------------------------
__global__ __launch_bounds__(256) void count_deg(
    const int* __restrict__ dst, int* __restrict__ cnt, int E)
{
    int i = (blockIdx.x * 256 + threadIdx.x) * 4;
    if (i + 3 < E) {
        int4 d = *(const int4*)&dst[i];
        atomicAdd(&cnt[d.x], 1);
        atomicAdd(&cnt[d.y], 1);
        atomicAdd(&cnt[d.z], 1);
        atomicAdd(&cnt[d.w], 1);
    } else {
        for (; i < E; ++i) atomicAdd(&cnt[dst[i]], 1);
    }
}

// ---------------------------------------------------------------------------
// Scan pass 1: each block scans 1024 counts (4/thread), emits block-local
// exclusive prefixes + block total.
// ---------------------------------------------------------------------------
__global__ __launch_bounds__(256) void scan_blk(
    const int* __restrict__ cnt, int* __restrict__ part,
    int* __restrict__ bsum, int N)
{
    __shared__ int wsum[4];
    int t = threadIdx.x, lane = t & 63, w = t >> 6;
    int base = blockIdx.x * 1024 + t * 4;
    int4 v = make_int4(0, 0, 0, 0);
    if (base + 3 < N) {
        v = *(const int4*)&cnt[base];
    } else {
        if (base     < N) v.x = cnt[base];
        if (base + 1 < N) v.y = cnt[base + 1];
        if (base + 2 < N) v.z = cnt[base + 2];
        if (base + 3 < N) v.w = cnt[base + 3];
    }
    int s = v.x + v.y + v.z + v.w;
    int sc = s;
    #pragma unroll
    for (int m = 1; m < 64; m <<= 1) {
        int u = __shfl_up(sc, m);
        if (lane >= m) sc += u;
    }
    if (lane == 63) wsum[w] = sc;
    __syncthreads();
    int woff = 0;
    for (int i = 0; i < w; ++i) woff += wsum[i];
    int excl = woff + sc - s;
    if (base     < N) part[base]     = excl;
    if (base + 1 < N) part[base + 1] = excl + v.x;
    if (base + 2 < N) part[base + 2] = excl + v.x + v.y;
    if (base + 3 < N) part[base + 3] = excl + v.x + v.y + v.z;
    if (t == 255) bsum[blockIdx.x] = woff + sc;
}

// ---------------------------------------------------------------------------
// Scan pass 2: single block scans block totals (nb <= 256).
// ---------------------------------------------------------------------------
__global__ __launch_bounds__(256) void scan_top(
    const int* __restrict__ bsum, int* __restrict__ boff, int nb)
{
    __shared__ int wsum[4];
    int t = threadIdx.x, lane = t & 63, w = t >> 6;
    int v = (t < nb) ? bsum[t] : 0;
    int sc = v;
    #pragma unroll
    for (int m = 1; m < 64; m <<= 1) {
        int u = __shfl_up(sc, m);
        if (lane >= m) sc += u;
    }
    if (lane == 63) wsum[w] = sc;
    __syncthreads();
    int woff = 0;
    for (int i = 0; i < w; ++i) woff += wsum[i];
    if (t < nb) boff[t] = woff + sc - v;
}

// ---------------------------------------------------------------------------
// Scan pass 3: globalize, write offsets + mutable cursor copy.
// ---------------------------------------------------------------------------
__global__ __launch_bounds__(256) void scan_add(
    const int* __restrict__ part, const int* __restrict__ boff,
    int* __restrict__ offsets, int* __restrict__ cursor, int N, int E)
{
    int i = blockIdx.x * 256 + threadIdx.x;
    if (i < N) {
        int o = part[i] + boff[i >> 10];
        offsets[i] = o;
        cursor[i]  = o;
    }
    if (i == 0) offsets[N] = E;
}

// ---------------------------------------------------------------------------
// CSR build pass 2: scatter edge source ids into segments. int4-batched.
// ---------------------------------------------------------------------------
__global__ __launch_bounds__(256) void fill_csr(
    const int* __restrict__ src, const int* __restrict__ dst,
    int* __restrict__ cursor, int* __restrict__ eidx, int E)
{
    int i = (blockIdx.x * 256 + threadIdx.x) * 4;
    if (i + 3 < E) {
        int4 d = *(const int4*)&dst[i];
        int4 s = *(const int4*)&src[i];
        int p0 = atomicAdd(&cursor[d.x], 1);
        int p1 = atomicAdd(&cursor[d.y], 1);
        int p2 = atomicAdd(&cursor[d.z], 1);
        int p3 = atomicAdd(&cursor[d.w], 1);
        eidx[p0] = s.x;
        eidx[p1] = s.y;
        eidx[p2] = s.z;
        eidx[p3] = s.w;
    } else {
        for (; i < E; ++i) {
            int p = atomicAdd(&cursor[dst[i]], 1);
            eidx[p] = src[i];
        }
    }
}

// ---------------------------------------------------------------------------
// Fused gather + update. One wave per node, 8 waves/block share one LDS W.
// Gather: float4 row-quarters — lane group g=(lane>>4) covers neighbor j+g,
// each lane loads a float4 (16B) so ONE global_load_dwordx4 per lane covers
// 4 neighbor rows. 2 accumulators keep 2 loads in flight (8 neighbors/iter).
// Cross-group reduce (8 shfl_xor) once per node, then the verified
// LDS-staged matmul / L2-normalize / relu / residual epilogue.
// ---------------------------------------------------------------------------
__global__ __launch_bounds__(512, 4) void sage_fused(
    const float* __restrict__ h, const float* __restrict__ W,
    const float* __restrict__ b, const int* __restrict__ offsets,
    const int* __restrict__ eidx, float* __restrict__ out, int N)
{
    __shared__ float Wp[DF * WSTRIDE];   // ~33 KB
    __shared__ float bs[DF];
    __shared__ float xbuf[8][128];

    for (int i = threadIdx.x; i < DF * 128; i += 512) {
        int o = i >> 7, k = i & 127;
        Wp[o * WSTRIDE + k] = W[i];
    }
    if (threadIdx.x < DF) bs[threadIdx.x] = b[threadIdx.x];
    __syncthreads();

    const int wave = threadIdx.x >> 6;
    const int lane = threadIdx.x & 63;
    const int g    = lane >> 4;        // neighbor sub-slot 0..3
    const int fo   = (lane & 15) * 4;  // float4 feature offset
    const int gw = blockIdx.x * 8 + wave;
    const int nw = gridDim.x * 8;
    float* xb = xbuf[wave];
    const float* wrow = &Wp[lane * WSTRIDE];
    const float bias = bs[lane];

    for (int n = gw; n < N; n += nw) {
        int beg = offsets[n];
        int end = offsets[n + 1];
        float hv = h[(size_t)n * DF + lane];

        // --- gather-sum neighbors (float4 row-quarters) ---
        float4 acc0 = make_float4(0.f, 0.f, 0.f, 0.f);
        float4 acc1 = make_float4(0.f, 0.f, 0.f, 0.f);
        for (int base = beg; base < end; base += 64) {
            int m = end - base;
            if (m > 64) m = 64;
            int idx = (lane < m) ? eidx[base + lane] : 0;
            for (int j = 0; j < m; j += 8) {
                int n0 = j + g;
                int n1 = j + 4 + g;
                int id0 = __shfl(idx, n0 & 63);
                int id1 = __shfl(idx, n1 & 63);
                if (n0 < m) {
                    float4 v = *(const float4*)&h[(size_t)id0 * DF + fo];
                    acc0.x += v.x; acc0.y += v.y; acc0.z += v.z; acc0.w += v.w;
                }
                if (n1 < m) {
                    float4 v = *(const float4*)&h[(size_t)id1 * DF + fo];
                    acc1.x += v.x; acc1.y += v.y; acc1.z += v.z; acc1.w += v.w;
                }
            }
        }
        acc0.x += acc1.x; acc0.y += acc1.y; acc0.z += acc1.z; acc0.w += acc1.w;
        // reduce across the 4 lane groups (lane^16, lane^32)
        #pragma unroll
        for (int m = 16; m < 64; m <<= 1) {
            acc0.x += __shfl_xor(acc0.x, m);
            acc0.y += __shfl_xor(acc0.y, m);
            acc0.z += __shfl_xor(acc0.z, m);
            acc0.w += __shfl_xor(acc0.w, m);
        }

        float dg = (float)(end - beg);
        float inv = 1.0f / fmaxf(dg, 1.0f);

        // --- stage x = [h, c] in per-wave LDS ---
        xb[lane] = hv;
        if (g == 0) {  // lanes 0..15 hold the full feature sum
            float4 cvec;
            cvec.x = acc0.x * inv; cvec.y = acc0.y * inv;
            cvec.z = acc0.z * inv; cvec.w = acc0.w * inv;
            *(float4*)&xb[DF + fo] = cvec;
        }
        // wave-synchronous LDS: no block barrier needed

        // --- y = [h,c]·W^T + b ---
        float y = bias;
        #pragma unroll
        for (int k = 0; k < 128; k += 4) {
            float4 xk = *(const float4*)&xb[k];    // same-address broadcast
            float4 wk = *(const float4*)&wrow[k];
            y += xk.x * wk.x;
            y += xk.y * wk.y;
            y += xk.z * wk.z;
            y += xk.w * wk.w;
        }

        // L2 norm across 64 lanes
        float ss = y * y;
        #pragma unroll
        for (int m = 1; m < 64; m <<= 1) ss += __shfl_xor(ss, m);

        float norm = sqrtf(ss);
        float nb2 = y / fmaxf(norm, 1e-12f);
        float nh = fmaxf(nb2, 0.0f);
        float hupd = (dg > 0.0f) ? nh : hv;
        out[(size_t)n * DF + lane] = hv + hupd;
    }
}

extern "C" void kernel_launch(void* const* d_in, const int* in_sizes, int n_in,
                              void* d_out, int out_size, void* d_ws, size_t ws_size,
                              hipStream_t stream) {
    const float* h   = (const float*)d_in[0];
    const float* W   = (const float*)d_in[1];
    const float* b   = (const float*)d_in[2];
    const int*   src = (const int*)d_in[3];
    const int*   dst = (const int*)d_in[4];
    float* out = (float*)d_out;

    const int N = in_sizes[0] / DF;
    const int E = in_sizes[3];

    // workspace carve (ints, 16B-aligned sections)
    int* cnt     = (int*)d_ws;                 // N
    int* part    = cnt     + ((N + 15) & ~15); // N
    int* bsum    = part    + ((N + 15) & ~15); // 256
    int* boff    = bsum    + 256;              // 256
    int* offsets = boff    + 256;              // N+1
    int* cursor  = offsets + ((N + 16) & ~15); // N
    int* eidx    = cursor  + ((N + 15) & ~15); // E

    hipMemsetAsync(cnt, 0, (size_t)N * sizeof(int), stream);

    int eb4 = (E / 4 + 255) / 256;  // int4-batched edge kernels
    count_deg<<<eb4, 256, 0, stream>>>(dst, cnt, E);

    int nb = (N + 1023) / 1024;
    scan_blk<<<nb, 256, 0, stream>>>(cnt, part, bsum, N);
    scan_top<<<1, 256, 0, stream>>>(bsum, boff, nb);
    scan_add<<<(N + 255) / 256, 256, 0, stream>>>(part, boff, offsets, cursor, N, E);

    fill_csr<<<eb4, 256, 0, stream>>>(src, dst, cursor, eidx, E);

    sage_fused<<<2048, 512, 0, stream>>>(h, W, b, offsets, eidx, out, N);
}

// Round 5
// 381.430 us; speedup vs baseline: 2.7750x; 1.1302x over previous
//
#include <hip/hip_runtime.h>

#define DF 64       // feature dim
#define WSTRIDE 132 // LDS row stride for W (mult of 4 keeps 16B align; %32==4 spreads banks)
#define ELLK 48     // ELL width; max degree of this input ~40 (uniform E/N=16 avg)

__device__ __forceinline__ unsigned short bf16rne(float f) {
    unsigned u = __float_as_uint(f);
    unsigned r = u + 0x7fffu + ((u >> 16) & 1u);  // round-to-nearest-even
    return (unsigned short)(r >> 16);
}
__device__ __forceinline__ float b2f(unsigned short u) {
    return __uint_as_float((unsigned)u << 16);
}

// ---------------------------------------------------------------------------
// h (fp32) -> hb (bf16): halves the random-gather bytes in the fused kernel.
// ---------------------------------------------------------------------------
__global__ __launch_bounds__(256) void conv_bf16(
    const float* __restrict__ h, unsigned short* __restrict__ hb, int total)
{
    int i = (blockIdx.x * 256 + threadIdx.x) * 4;
    if (i + 3 < total) {
        float4 v = *(const float4*)&h[i];
        ushort4 o;
        o.x = bf16rne(v.x); o.y = bf16rne(v.y);
        o.z = bf16rne(v.z); o.w = bf16rne(v.w);
        *(ushort4*)&hb[i] = o;
    } else {
        for (; i < total; ++i) hb[i] = bf16rne(h[i]);
    }
}

// ---------------------------------------------------------------------------
// One-pass ELL build: slot = atomicAdd(cnt[dst]); ell[dst*ELLK+slot] = src.
// Overflow (slot >= ELLK) goes to a (dst,src) list -> handled by a slow path
// in the fused kernel. For this input the list stays empty.
// ---------------------------------------------------------------------------
__device__ __forceinline__ void ell_push(
    int d, int s, int* cnt, int* ell, int* ovf, int* ovfcnt, int cap)
{
    int slot = atomicAdd(&cnt[d], 1);
    if (slot < ELLK) {
        ell[(size_t)d * ELLK + slot] = s;
    } else {
        int p = atomicAdd(ovfcnt, 1);
        if (p < cap) { ovf[2 * p] = d; ovf[2 * p + 1] = s; }
    }
}

__global__ __launch_bounds__(256) void fill_ell(
    const int* __restrict__ src, const int* __restrict__ dst,
    int* __restrict__ cnt, int* __restrict__ ell,
    int* __restrict__ ovf, int* __restrict__ ovfcnt, int ovfcap, int E)
{
    int i = (blockIdx.x * 256 + threadIdx.x) * 4;
    if (i + 3 < E) {
        int4 d = *(const int4*)&dst[i];
        int4 s = *(const int4*)&src[i];
        ell_push(d.x, s.x, cnt, ell, ovf, ovfcnt, ovfcap);
        ell_push(d.y, s.y, cnt, ell, ovf, ovfcnt, ovfcap);
        ell_push(d.z, s.z, cnt, ell, ovf, ovfcnt, ovfcap);
        ell_push(d.w, s.w, cnt, ell, ovf, ovfcnt, ovfcap);
    } else {
        for (; i < E; ++i) ell_push(dst[i], src[i], cnt, ell, ovf, ovfcnt, ovfcap);
    }
}

// ---------------------------------------------------------------------------
// Fused gather + update. One wave per node; 8 waves/block share one LDS W.
// Gather from bf16 hb: lane group g=(lane>>4) covers neighbor rows j+g,
// j+4+g, j+8+g, j+12+g; each lane loads ushort4 (8B = 4 feats), so 4
// independent 8B loads per 16 neighbors stay in flight.
// Epilogue (verified rounds 1-4): LDS-staged x, W-row dot, L2-normalize,
// relu, where(deg>0), residual.
// ---------------------------------------------------------------------------
__global__ __launch_bounds__(512, 4) void sage_fused(
    const float* __restrict__ h, const unsigned short* __restrict__ hb,
    const float* __restrict__ W, const float* __restrict__ b,
    const int* __restrict__ cnt, const int* __restrict__ ell,
    const int* __restrict__ ovf, const int* __restrict__ ovfcnt,
    int ovfcap, float* __restrict__ out, int N)
{
    __shared__ float Wp[DF * WSTRIDE];   // ~33 KB
    __shared__ float bs[DF];
    __shared__ float xbuf[8][128];

    for (int i = threadIdx.x; i < DF * 128; i += 512) {
        int o = i >> 7, k = i & 127;
        Wp[o * WSTRIDE + k] = W[i];
    }
    if (threadIdx.x < DF) bs[threadIdx.x] = b[threadIdx.x];
    __syncthreads();

    const int wave = threadIdx.x >> 6;
    const int lane = threadIdx.x & 63;
    const int g    = lane >> 4;        // neighbor sub-slot 0..3
    const int fo   = (lane & 15) * 4;  // 4-feature offset within a row
    const int gw = blockIdx.x * 8 + wave;
    const int nw = gridDim.x * 8;
    float* xb = xbuf[wave];
    const float* wrow = &Wp[lane * WSTRIDE];
    const float bias = bs[lane];

    for (int n = gw; n < N; n += nw) {
        int deg = cnt[n];
        int m = deg < ELLK ? deg : ELLK;
        float hv = h[(size_t)n * DF + lane];

        int idx = (lane < m) ? ell[(size_t)n * ELLK + lane] : 0;

        float4 a0 = make_float4(0.f, 0.f, 0.f, 0.f);
        float4 a1 = make_float4(0.f, 0.f, 0.f, 0.f);
        float4 a2 = make_float4(0.f, 0.f, 0.f, 0.f);
        float4 a3 = make_float4(0.f, 0.f, 0.f, 0.f);
        for (int j = 0; j < m; j += 16) {
            int i0 = j + g, i1 = j + g + 4, i2 = j + g + 8, i3 = j + g + 12;
            int id0 = __shfl(idx, i0 & 63);
            int id1 = __shfl(idx, i1 & 63);
            int id2 = __shfl(idx, i2 & 63);
            int id3 = __shfl(idx, i3 & 63);
            if (i0 < m) {
                ushort4 u = *(const ushort4*)&hb[(size_t)id0 * DF + fo];
                a0.x += b2f(u.x); a0.y += b2f(u.y); a0.z += b2f(u.z); a0.w += b2f(u.w);
            }
            if (i1 < m) {
                ushort4 u = *(const ushort4*)&hb[(size_t)id1 * DF + fo];
                a1.x += b2f(u.x); a1.y += b2f(u.y); a1.z += b2f(u.z); a1.w += b2f(u.w);
            }
            if (i2 < m) {
                ushort4 u = *(const ushort4*)&hb[(size_t)id2 * DF + fo];
                a2.x += b2f(u.x); a2.y += b2f(u.y); a2.z += b2f(u.z); a2.w += b2f(u.w);
            }
            if (i3 < m) {
                ushort4 u = *(const ushort4*)&hb[(size_t)id3 * DF + fo];
                a3.x += b2f(u.x); a3.y += b2f(u.y); a3.z += b2f(u.z); a3.w += b2f(u.w);
            }
        }
        a0.x += a1.x + a2.x + a3.x;
        a0.y += a1.y + a2.y + a3.y;
        a0.z += a1.z + a2.z + a3.z;
        a0.w += a1.w + a2.w + a3.w;
        #pragma unroll
        for (int s = 16; s < 64; s <<= 1) {
            a0.x += __shfl_xor(a0.x, s);
            a0.y += __shfl_xor(a0.y, s);
            a0.z += __shfl_xor(a0.z, s);
            a0.w += __shfl_xor(a0.w, s);
        }

        // overflow slow path (deg > ELLK): scan (dst,src) list, exact fp32
        float extra = 0.f;
        if (deg > ELLK) {
            int oc = *ovfcnt; if (oc > ovfcap) oc = ovfcap;
            for (int t = 0; t < oc; ++t) {
                int d2 = ovf[2 * t];
                if (d2 == n) extra += h[(size_t)ovf[2 * t + 1] * DF + lane];
            }
        }

        float dg = (float)deg;
        float inv = 1.0f / fmaxf(dg, 1.0f);

        // stage x = [h, c] in per-wave LDS (wave-synchronous, no barrier)
        if (g == 0) *(float4*)&xb[DF + fo] = a0;  // raw sums, lanes 0..15
        xb[lane] = hv;
        float cv = (xb[DF + lane] + extra) * inv;
        xb[DF + lane] = cv;

        // y = [h,c]·W^T + b
        float y = bias;
        #pragma unroll
        for (int k = 0; k < 128; k += 4) {
            float4 xk = *(const float4*)&xb[k];    // same-address broadcast
            float4 wk = *(const float4*)&wrow[k];
            y += xk.x * wk.x;
            y += xk.y * wk.y;
            y += xk.z * wk.z;
            y += xk.w * wk.w;
        }

        // L2 norm across 64 lanes
        float ss = y * y;
        #pragma unroll
        for (int s = 1; s < 64; s <<= 1) ss += __shfl_xor(ss, s);

        float norm = sqrtf(ss);
        float nb2 = y / fmaxf(norm, 1e-12f);
        float nh = fmaxf(nb2, 0.0f);
        float hupd = (dg > 0.0f) ? nh : hv;
        out[(size_t)n * DF + lane] = hv + hupd;
    }
}

extern "C" void kernel_launch(void* const* d_in, const int* in_sizes, int n_in,
                              void* d_out, int out_size, void* d_ws, size_t ws_size,
                              hipStream_t stream) {
    const float* h   = (const float*)d_in[0];
    const float* W   = (const float*)d_in[1];
    const float* b   = (const float*)d_in[2];
    const int*   src = (const int*)d_in[3];
    const int*   dst = (const int*)d_in[4];
    float* out = (float*)d_out;

    const int N = in_sizes[0] / DF;
    const int E = in_sizes[3];

    // workspace carve
    int* cnt    = (int*)d_ws;                       // N
    int* ovfcnt = cnt + ((N + 15) & ~15);           // 16 (adjacent -> 1 memset)
    int* ell    = ovfcnt + 16;                      // N * ELLK
    unsigned short* hb = (unsigned short*)(ell + ((size_t)N * ELLK + 15) / 16 * 16);
    int* ovf    = (int*)(hb + ((size_t)N * DF + 15) / 16 * 16);
    size_t used = (size_t)((char*)ovf - (char*)d_ws);
    int ovfcap  = (ws_size > used + 64) ? (int)((ws_size - used) / 8 - 4) : 0;

    // zero degree counters + overflow counter (ws poisoned 0xAA each launch)
    hipMemsetAsync(cnt, 0, ((size_t)((N + 15) & ~15) + 16) * sizeof(int), stream);

    conv_bf16<<<((N * DF) / 4 + 255) / 256, 256, 0, stream>>>(h, hb, N * DF);

    fill_ell<<<(E / 4 + 255) / 256, 256, 0, stream>>>(
        src, dst, cnt, ell, ovf, ovfcnt, ovfcap, E);

    sage_fused<<<2048, 512, 0, stream>>>(
        h, hb, W, b, cnt, ell, ovf, ovfcnt, ovfcap, out, N);
}